// Round 11
// baseline (26.289 us; speedup 1.0000x reference)
//
#include <hip/hip_runtime.h>

#define KP 137
#define SS 512
#define BB 128
#define STRIP 8
#define NSTRIP (SS / STRIP)          // 64 strips per batch
#define NWAVE (BB * NSTRIP)          // 8192 waves
#define THREADS 128                  // 2 independent waves per block
#define NBLK (NWAVE / 2)             // 4096 blocks

// Lane -> keypoint-PAIR mapping: lane l owns kps (2l, 2l+1) -> pred float4,
// target float2 per plane. Tail kps 128..136 on lanes 0..4 (lane4 = kps
// (135,136), first elem duplicate of lane3 and masked).
// Bone pairs (136 total): in-lane (2l,2l+1) x64; cross (2l+1,2l+2) lanes<63;
// boundary (127,128) on lane63 via broadcast of tail-lane0 e0; tail in-lane
// x4 (lanes0-3); tail cross x3 (lanes0-2); pair (135,136) on lane3 via
// shfl of lane4's e1. Pose: 128 main kps + tail lanes0-3 both + lane4 second.
// NOTE: no __threadfence/fused finisher (r5/r6/r9: per-block device fence
// collapses the kernel to ~200 GB/s). Two launches, no fences.

__global__ __launch_bounds__(THREADS) void t2p_main(
    const float* __restrict__ pred,      // [B,S,2K]
    const float* __restrict__ tgt,       // [B,2,S,K]
    const int*   __restrict__ tlen,      // [B]
    float2* __restrict__ partials)       // [NBLK]
{
    __shared__ float2 wsum[2];

    const int t    = threadIdx.x;
    const int lane = t & 63;
    const int wid  = t >> 6;
    const int w    = blockIdx.x * 2 + wid;   // global wave id, 0..8191
    const int b    = w >> 6;                 // NSTRIP = 64 strips per batch
    const int s0   = (w & (NSTRIP - 1)) * STRIP;
    const int len  = tlen[b];

    float pose = 0.f, bone = 0.f;

    if (s0 < len) {                          // wave-uniform; no barriers inside
        const int send = (len < s0 + STRIP) ? len : (s0 + STRIP);
        const float* txp = tgt + (size_t)(2 * b) * SS * KP;   // x plane
        const float* typ = txp + (size_t)SS * KP;             // y plane
        const float* pp  = pred + (size_t)b * SS * (2 * KP);

        const bool lt = (lane < 5);
        const int k0 = 2 * lane;                             // kps 0..127
        const int kt = (lane < 4) ? (128 + 2 * lane) : 135;  // tail kps

        // rolling same-row target state (row s0)
        float2 tx0, ty0, txt0, tyt0;
        {
            const float* r = txp + s0 * KP;
            const float* q = typ + s0 * KP;
            tx0 = *(const float2*)(r + k0);
            ty0 = *(const float2*)(q + k0);
            txt0 = lt ? *(const float2*)(r + kt) : make_float2(0.f, 0.f);
            tyt0 = lt ? *(const float2*)(q + kt) : make_float2(0.f, 0.f);
        }

        for (int s = s0; s < send; ++s) {
            // ---- loads: 3 full-wave + 3 five-lane-masked VMEM ----
            const float* prow = pp + (size_t)s * (2 * KP);
            float4 p  = *(const float4*)(prow + 2 * k0);     // x0,y0,x1,y1
            float4 pt = lt ? *(const float4*)(prow + 2 * kt)
                           : make_float4(0.f, 0.f, 0.f, 0.f);

            const int sn = (s + 1 < SS) ? s + 1 : SS - 1;    // clamp; masked
            const float* r = txp + sn * KP;
            const float* q = typ + sn * KP;
            float2 tx1  = *(const float2*)(r + k0);
            float2 ty1  = *(const float2*)(q + k0);
            float2 txt1 = lt ? *(const float2*)(r + kt) : make_float2(0.f, 0.f);
            float2 tyt1 = lt ? *(const float2*)(q + kt) : make_float2(0.f, 0.f);

            // ---- pose: pred row s vs target row s+1 ----
            if (s < len - 1) {                // wave-uniform
                float acc = fabsf(p.x - tx1.x) + fabsf(p.y - ty1.x)
                          + fabsf(p.z - tx1.y) + fabsf(p.w - ty1.y);
                if (lt) {
                    float a1 = fabsf(pt.z - txt1.y) + fabsf(pt.w - tyt1.y);
                    if (lane < 4)
                        acc += a1 + fabsf(pt.x - txt1.x) + fabsf(pt.y - tyt1.x);
                    else
                        acc += a1;            // lane4: kp136 only
                }
                pose += acc;
            }

            // ---- bone: e = pred - target(row s) ----
            float e0x = p.x - tx0.x, e0y = p.y - ty0.x;      // kp 2l
            float e1x = p.z - tx0.y, e1y = p.w - ty0.y;      // kp 2l+1
            float et0x = pt.x - txt0.x, et0y = pt.y - tyt0.x; // kp kt
            float et1x = pt.z - txt0.y, et1y = pt.w - tyt0.y; // kp kt+1

            float n0x = __shfl_down(e0x, 1, 64);   // next lane's e0
            float n0y = __shfl_down(e0y, 1, 64);
            float b0x = __shfl(et0x, 0, 64);       // tail lane0 e0 = kp128
            float b0y = __shfl(et0y, 0, 64);
            float m0x = __shfl_down(et0x, 1, 64);  // next tail lane's e0
            float m0y = __shfl_down(et0y, 1, 64);
            float m1x = __shfl_down(et1x, 1, 64);  // next tail lane's e1
            float m1y = __shfl_down(et1y, 1, 64);

            float dx = e1x - e0x, dy = e1y - e0y;            // (2l, 2l+1)
            float acc = dx * dx + dy * dy;
            if (lane < 63) {                                 // (2l+1, 2l+2)
                dx = n0x - e1x; dy = n0y - e1y;
                acc += dx * dx + dy * dy;
            } else {                                         // (127, 128)
                dx = b0x - e1x; dy = b0y - e1y;
                acc += dx * dx + dy * dy;
            }
            if (lane < 4) {                                  // (kt, kt+1)
                dx = et1x - et0x; dy = et1y - et0y;
                acc += dx * dx + dy * dy;
            }
            if (lane < 3) {                                  // (kt+1, kt+2)
                dx = m0x - et1x; dy = m0y - et1y;
                acc += dx * dx + dy * dy;
            }
            if (lane == 3) {                                 // (135, 136)
                dx = m1x - et1x; dy = m1y - et1y;
                acc += dx * dx + dy * dy;
            }
            bone += acc;

            // roll target row s+1 -> same-row state for next iteration
            tx0 = tx1; ty0 = ty1; txt0 = txt1; tyt0 = tyt1;
        }
    }

    // per-wave reduce, then tiny 2-wave block fold (single barrier)
    for (int off = 32; off > 0; off >>= 1) {
        pose += __shfl_down(pose, off, 64);
        bone += __shfl_down(bone, off, 64);
    }
    if (lane == 0) wsum[wid] = make_float2(pose, bone);
    __syncthreads();
    if (t == 0) {
        partials[blockIdx.x] = make_float2(wsum[0].x + wsum[1].x,
                                           wsum[0].y + wsum[1].y);
    }
}

__global__ __launch_bounds__(1024) void t2p_final(
    const float2* __restrict__ partials,
    const int* __restrict__ tlen,
    float* __restrict__ out)
{
    const int t = threadIdx.x;
    float ps = 0.f, bs = 0.f;
    #pragma unroll
    for (int i = 0; i < NBLK / 1024; ++i) {      // 4 each
        float2 v = partials[t + i * 1024];
        ps += v.x; bs += v.y;
    }
    float pc = 0.f, mc = 0.f;
    if (t < BB) {
        int L = tlen[t];
        pc = (float)(L - 1);   // sum(pose_mask)
        mc = (float)L;         // sum(mask)
    }
    for (int off = 32; off > 0; off >>= 1) {
        ps += __shfl_down(ps, off, 64);
        bs += __shfl_down(bs, off, 64);
        pc += __shfl_down(pc, off, 64);
        mc += __shfl_down(mc, off, 64);
    }
    __shared__ float4 wsum[16];
    if ((t & 63) == 0) wsum[t >> 6] = make_float4(ps, bs, pc, mc);
    __syncthreads();
    if (t == 0) {
        float4 a = wsum[0];
        #pragma unroll
        for (int i = 1; i < 16; ++i) {
            a.x += wsum[i].x; a.y += wsum[i].y;
            a.z += wsum[i].z; a.w += wsum[i].w;
        }
        float pose_loss = a.x / (274.f * a.z);
        float bone_loss = (a.y * 0.5f) / ((136.f + 1e-8f) * a.w);
        out[0] = pose_loss + 0.1f * bone_loss;   // POSE_W=1, BONE_W=0.1
        out[1] = pose_loss;
        out[2] = bone_loss;
    }
}

extern "C" void kernel_launch(void* const* d_in, const int* in_sizes, int n_in,
                              void* d_out, int out_size, void* d_ws, size_t ws_size,
                              hipStream_t stream) {
    const float* pred = (const float*)d_in[0];   // [128,512,274] f32
    const float* tgt  = (const float*)d_in[1];   // [128,2,512,137] f32
    const int*   tlen = (const int*)d_in[2];     // [128] i32
    float* out = (float*)d_out;
    float2* partials = (float2*)d_ws;            // 4096 * 8 B = 32 KB

    t2p_main<<<NBLK, THREADS, 0, stream>>>(pred, tgt, tlen, partials);
    t2p_final<<<1, 1024, 0, stream>>>(partials, tlen, out);
}

// Round 12
// 24.479 us; speedup vs baseline: 1.0740x; 1.0740x over previous
//
#include <hip/hip_runtime.h>

#define KP 137
#define SS 512
#define BB 128
#define STRIP 8
#define NSTRIP (SS / STRIP)          // 64 strips per batch
#define TOTSTRIP (BB * NSTRIP)       // 8192 strips
#define THREADS 256                  // 4 independent waves per block
#define NBLKP 1024
#define NWAVES (NBLKP * 4)           // 4096 waves
#define SPW (TOTSTRIP / NWAVES)      // 2 strips per wave, stride-assigned

// Lane -> keypoint mapping (3 overlapped sub-batches so every bone pair is
// intra-sub-batch): a = kp lane (0..63), b = kp 63+lane (63..126),
// c = kp 126+lane for lane<=10 (126..136).
// Pose counted once: a lanes 0..63, b lanes 1..63, c lanes 1..10.
// Bone pairs: a lane<63 (k 0..62), b lane<63 (k 63..125), c lane<10 (k 126..135).
// NOTE: no __threadfence/fused finisher (r5/r6/r9: per-block device fences
// collapse the kernel to ~200 GB/s). Persistent waves: each wave processes
// SPW strips (strip = i*NWAVES + gw) to amortize workgroup-handoff latency —
// r4..r11 showed all per-strip-workgroup structures plateau at 24 us.

__global__ __launch_bounds__(THREADS) void t2p_main(
    const float* __restrict__ pred,      // [B,S,2K]
    const float* __restrict__ tgt,       // [B,2,S,K]
    const int*   __restrict__ tlen,      // [B]
    float2* __restrict__ partials)       // [NBLKP]
{
    __shared__ float2 wsum[4];

    const int t    = threadIdx.x;
    const int lane = t & 63;
    const int wid  = t >> 6;
    const int gw   = blockIdx.x * 4 + wid;   // global wave id, 0..4095
    const bool lc  = (lane <= 10);

    float pose = 0.f, bone = 0.f;

    #pragma unroll
    for (int i = 0; i < SPW; ++i) {
        const int strip = i * NWAVES + gw;       // global front-to-back sweep
        const int b     = strip >> 6;            // NSTRIP = 64
        const int s0    = (strip & (NSTRIP - 1)) * STRIP;
        const int len   = tlen[b];
        if (s0 >= len) continue;                 // wave-uniform

        const int send = (len < s0 + STRIP) ? len : (s0 + STRIP);
        const float* txp = tgt + (size_t)(2 * b) * SS * KP;   // x plane
        const float* typ = txp + (size_t)SS * KP;             // y plane
        const float2* pp = (const float2*)(pred + (size_t)b * SS * (2 * KP));

        // rolling same-row target (row s0)
        float t0xa, t0xb, t0xc, t0ya, t0yb, t0yc;
        {
            const float* r = txp + s0 * KP;
            const float* q = typ + s0 * KP;
            t0xa = r[lane]; t0xb = r[63 + lane]; t0xc = lc ? r[126 + lane] : 0.f;
            t0ya = q[lane]; t0yb = q[63 + lane]; t0yc = lc ? q[126 + lane] : 0.f;
        }

        for (int s = s0; s < send; ++s) {
            const float2* pr = pp + (size_t)s * KP;
            float2 pa = pr[lane];
            float2 pb = pr[63 + lane];
            float2 pc = lc ? pr[126 + lane] : make_float2(0.f, 0.f);

            // branch-free target row load: clamp row index; garbage at s=511
            // is never accumulated (pose needs s < len-1 <= 510) and the
            // rolled t0 is never consumed (s=511 is the last iteration).
            const int sn = (s + 1 < SS) ? s + 1 : SS - 1;
            const float* r = txp + sn * KP;
            const float* q = typ + sn * KP;
            float t1xa = r[lane], t1xb = r[63 + lane];
            float t1xc = lc ? r[126 + lane] : 0.f;
            float t1ya = q[lane], t1yb = q[63 + lane];
            float t1yc = lc ? q[126 + lane] : 0.f;

            // pose: each kp counted once
            if (s < len - 1) {                   // wave-uniform
                float acc = fabsf(pa.x - t1xa) + fabsf(pa.y - t1ya);
                if (lane >= 1)       acc += fabsf(pb.x - t1xb) + fabsf(pb.y - t1yb);
                if (lane >= 1 && lc) acc += fabsf(pc.x - t1xc) + fabsf(pc.y - t1yc);
                pose += acc;
            }

            // e = pred - target (same row), bone via lane-shift
            float exa = pa.x - t0xa, eya = pa.y - t0ya;
            float exb = pb.x - t0xb, eyb = pb.y - t0yb;
            float exc = pc.x - t0xc, eyc = pc.y - t0yc;
            float nxa = __shfl_down(exa, 1, 64), nya = __shfl_down(eya, 1, 64);
            float nxb = __shfl_down(exb, 1, 64), nyb = __shfl_down(eyb, 1, 64);
            float nxc = __shfl_down(exc, 1, 64), nyc = __shfl_down(eyc, 1, 64);
            float acc = 0.f;
            if (lane < 63) {
                float dx = nxa - exa, dy = nya - eya; acc += dx * dx + dy * dy;
                float ex = nxb - exb, ey = nyb - eyb; acc += ex * ex + ey * ey;
            }
            if (lane < 10) {
                float dx = nxc - exc, dy = nyc - eyc; acc += dx * dx + dy * dy;
            }
            bone += acc;

            // roll: row s+1 target becomes next iteration's same-row target
            t0xa = t1xa; t0xb = t1xb; t0xc = t1xc;
            t0ya = t1ya; t0yb = t1yb; t0yc = t1yc;
        }
    }

    // per-wave reduce, then 4-wave block fold (single barrier at the end)
    for (int off = 32; off > 0; off >>= 1) {
        pose += __shfl_down(pose, off, 64);
        bone += __shfl_down(bone, off, 64);
    }
    if (lane == 0) wsum[wid] = make_float2(pose, bone);
    __syncthreads();
    if (t == 0) {
        float px = 0.f, bx = 0.f;
        #pragma unroll
        for (int i = 0; i < 4; ++i) { px += wsum[i].x; bx += wsum[i].y; }
        partials[blockIdx.x] = make_float2(px, bx);
    }
}

__global__ __launch_bounds__(256) void t2p_final(
    const float2* __restrict__ partials,
    const int* __restrict__ tlen,
    float* __restrict__ out)
{
    const int t = threadIdx.x;
    float ps = 0.f, bs = 0.f;
    #pragma unroll
    for (int i = 0; i < NBLKP / 256; ++i) {      // 4 each
        float2 v = partials[t + i * 256];
        ps += v.x; bs += v.y;
    }
    float pc = 0.f, mc = 0.f;
    if (t < BB) {
        int L = tlen[t];
        pc = (float)(L - 1);   // sum(pose_mask)
        mc = (float)L;         // sum(mask)
    }
    for (int off = 32; off > 0; off >>= 1) {
        ps += __shfl_down(ps, off, 64);
        bs += __shfl_down(bs, off, 64);
        pc += __shfl_down(pc, off, 64);
        mc += __shfl_down(mc, off, 64);
    }
    __shared__ float4 wsum[4];
    if ((t & 63) == 0) wsum[t >> 6] = make_float4(ps, bs, pc, mc);
    __syncthreads();
    if (t == 0) {
        float4 a = wsum[0];
        #pragma unroll
        for (int i = 1; i < 4; ++i) {
            a.x += wsum[i].x; a.y += wsum[i].y;
            a.z += wsum[i].z; a.w += wsum[i].w;
        }
        float pose_loss = a.x / (274.f * a.z);
        float bone_loss = (a.y * 0.5f) / ((136.f + 1e-8f) * a.w);
        out[0] = pose_loss + 0.1f * bone_loss;   // POSE_W=1, BONE_W=0.1
        out[1] = pose_loss;
        out[2] = bone_loss;
    }
}

extern "C" void kernel_launch(void* const* d_in, const int* in_sizes, int n_in,
                              void* d_out, int out_size, void* d_ws, size_t ws_size,
                              hipStream_t stream) {
    const float* pred = (const float*)d_in[0];   // [128,512,274] f32
    const float* tgt  = (const float*)d_in[1];   // [128,2,512,137] f32
    const int*   tlen = (const int*)d_in[2];     // [128] i32
    float* out = (float*)d_out;
    float2* partials = (float2*)d_ws;            // 1024 * 8 B = 8 KB

    t2p_main<<<NBLKP, THREADS, 0, stream>>>(pred, tgt, tlen, partials);
    t2p_final<<<1, 256, 0, stream>>>(partials, tlen, out);
}